// Round 3
// baseline (104.089 us; speedup 1.0000x reference)
//
#include <hip/hip_runtime.h>
#include <math.h>

// DirectVolumeRenderer, single-dispatch version.
// Block = 64 consecutive x-pixels (one half-row) x 8 ray segments x 32 samples.
//   wave s (0..7) renders segment s for all 64 pixels (lane = pixel-x, so each
//   gather instruction's 64 addresses span ~50-150 consecutive floats -> ~4-10
//   cache lines instead of 64; this is what took render 110us -> ~30us in R1).
// Segments composed through LDS (EA recurrence is associative), per-block
// stats partials to ws, then the LAST block (threadfence+atomic counter) does
// the global mean/std(ddof=1)/min/max reduction and the elementwise normalize.
// g is written in transposed (W,H) layout by the render phase so finalize is
// a pure coalesced elementwise pass.

#define FOCAL 1.7320508f

__global__ __launch_bounds__(512) void dvr_kernel(
    const float* __restrict__ img, const float* __restrict__ opa,
    const float* __restrict__ Rm, const float* __restrict__ Tv,
    float* __restrict__ g, double* __restrict__ bstats,
    unsigned int* __restrict__ counter, float* __restrict__ out)
{
  const int tid  = threadIdx.x;
  const int lane = tid & 63;
  const int seg  = tid >> 6;            // wave id = segment 0..7
  const int b    = blockIdx.x;          // 0..255: half-row id
  const int h    = b >> 1;
  const int w    = ((b & 1) << 6) | lane;

  // camera (row-vector convention): origin = -T @ R^T ; dir_world = dir_cam @ R^T
  const float R00=Rm[0], R01=Rm[1], R02=Rm[2];
  const float R10=Rm[3], R11=Rm[4], R12=Rm[5];
  const float R20=Rm[6], R21=Rm[7], R22=Rm[8];
  const float T0=Tv[0], T1=Tv[1], T2=Tv[2];

  const float ox = -(T0*R00 + T1*R01 + T2*R02);
  const float oy = -(T0*R10 + T1*R11 + T2*R12);
  const float oz = -(T0*R20 + T1*R21 + T2*R22);

  const float gx = 1.0f - (2.0f/127.0f) * (float)w;   // xs = linspace(1,-1,128)
  const float gy = 1.0f - (2.0f/127.0f) * (float)h;
  const float dcx = gx * (1.0f/FOCAL);
  const float dcy = gy * (1.0f/FOCAL);
  const float dwx = dcx*R00 + dcy*R01 + R02;
  const float dwy = dcx*R10 + dcy*R11 + R12;
  const float dwz = dcx*R20 + dcy*R21 + R22;

  // half_extent = (3/128)*127/2 = 1.48828125; voxel coord = (p/he + 1)*63.5
  const float s_he = (1.0f/1.48828125f) * 63.5f;
  const float ax = dwx * s_he, bxc = ox * s_he + 63.5f;
  const float ay = dwy * s_he, byc = oy * s_he + 63.5f;
  const float az = dwz * s_he, bzc = oz * s_he + 63.5f;

  const int p0 = seg << 5;              // 32 samples per segment

  float lp = 1.0f;     // transmittance across this segment
  float accl = 0.0f;   // weighted feature sum relative to segment start

  for (int j = 0; j < 32; ++j) {
    const float depth = 2.0f + (4.0f/255.0f) * (float)(p0 + j);  // linspace(2,6,256)
    const float x = bxc + depth * ax;
    const float y = byc + depth * ay;
    const float z = bzc + depth * az;
    const float x0f = floorf(x), y0f = floorf(y), z0f = floorf(z);
    const float wx = x - x0f, wy = y - y0f, wz = z - z0f;
    const int x0 = (int)x0f, y0 = (int)y0f, z0 = (int)z0f;

    float feat = 0.0f, dens = 0.0f;
    if (x0 >= -1 && x0 <= 127 && y0 >= -1 && y0 <= 127 &&
        z0 >= -1 && z0 <= 127) {
      const float fx0 = (x0 >= 0)   ? (1.0f - wx) : 0.0f;
      const float fx1 = (x0 <= 126) ? wx          : 0.0f;
      const float fy0 = (y0 >= 0)   ? (1.0f - wy) : 0.0f;
      const float fy1 = (y0 <= 126) ? wy          : 0.0f;
      const float fz0 = (z0 >= 0)   ? (1.0f - wz) : 0.0f;
      const float fz1 = (z0 <= 126) ? wz          : 0.0f;
      const int ix0 = (x0 >= 0)   ? x0     : 0;
      const int ix1 = (x0 <= 126) ? x0 + 1 : 127;
      const int iy0 = ((y0 >= 0)   ? y0     : 0)   << 7;
      const int iy1 = ((y0 <= 126) ? y0 + 1 : 127) << 7;
      const int iz0 = ((z0 >= 0)   ? z0     : 0)   << 14;
      const int iz1 = ((z0 <= 126) ? z0 + 1 : 127) << 14;

      const int b00 = iz0 + iy0, b01 = iz0 + iy1;
      const int b10 = iz1 + iy0, b11 = iz1 + iy1;
      const float w00 = fz0*fy0, w01 = fz0*fy1, w10 = fz1*fy0, w11 = fz1*fy1;

      feat = w00*(fx0*img[b00+ix0] + fx1*img[b00+ix1])
           + w01*(fx0*img[b01+ix0] + fx1*img[b01+ix1])
           + w10*(fx0*img[b10+ix0] + fx1*img[b10+ix1])
           + w11*(fx0*img[b11+ix0] + fx1*img[b11+ix1]);
      dens = w00*(fx0*opa[b00+ix0] + fx1*opa[b00+ix1])
           + w01*(fx0*opa[b01+ix0] + fx1*opa[b01+ix1])
           + w10*(fx0*opa[b10+ix0] + fx1*opa[b10+ix1])
           + w11*(fx0*opa[b11+ix0] + fx1*opa[b11+ix1]);
    }
    const float d = dens * 0.1f;       // SCALING
    accl += feat * d * lp;             // weight = dens * incoming transmittance
    lp   *= (1.0f - d);                // (1+1e-10)-d == 1-d in f32
  }

  __shared__ float2 slp[8][64];
  slp[seg][lane] = make_float2(accl, lp);
  __syncthreads();

  // ---- per-block combine (wave 0) + stats partial ----
  if (tid < 64) {
    float T = 1.0f, acc = 0.0f;
    #pragma unroll
    for (int s = 0; s < 8; ++s) {
      const float2 v = slp[s][tid];
      acc += v.x * T;
      T *= v.y;
    }
    const int ww = ((b & 1) << 6) | tid;
    g[(ww << 7) + h] = acc;            // transposed (W,H) layout

    double sum = (double)acc;
    double sq  = (double)acc * (double)acc;
    float mn = acc, mx = acc;
    #pragma unroll
    for (int off = 32; off >= 1; off >>= 1) {
      sum += __shfl_xor(sum, off, 64);
      sq  += __shfl_xor(sq,  off, 64);
      mn = fminf(mn, __shfl_xor(mn, off, 64));
      mx = fmaxf(mx, __shfl_xor(mx, off, 64));
    }
    if (tid == 0) {
      bstats[(b << 2) + 0] = sum;
      bstats[(b << 2) + 1] = sq;
      bstats[(b << 2) + 2] = (double)mn;
      bstats[(b << 2) + 3] = (double)mx;
    }
  }
  __syncthreads();

  // ---- last-block-finalize handshake ----
  __shared__ int is_last;
  if (tid == 0) {
    __threadfence();                                  // publish g + bstats
    const unsigned int old = atomicAdd(counter, 1u);  // device-scope
    is_last = (old == gridDim.x - 1) ? 1 : 0;
  }
  __syncthreads();
  if (!is_last) return;
  __threadfence();                                    // acquire

  // ---- global stats reduction (256 partials, 512 threads) ----
  double S = 0.0, Q = 0.0;
  float MN = 3.402823466e38f, MX = -3.402823466e38f;
  if (tid < 256) {
    S  = bstats[(tid << 2) + 0];
    Q  = bstats[(tid << 2) + 1];
    MN = (float)bstats[(tid << 2) + 2];
    MX = (float)bstats[(tid << 2) + 3];
  }
  #pragma unroll
  for (int off = 32; off >= 1; off >>= 1) {
    S += __shfl_xor(S, off, 64);
    Q += __shfl_xor(Q, off, 64);
    MN = fminf(MN, __shfl_xor(MN, off, 64));
    MX = fmaxf(MX, __shfl_xor(MX, off, 64));
  }
  __shared__ double rs[8], rq[8];
  __shared__ float rmn[8], rmx[8];
  if (lane == 0) { rs[seg] = S; rq[seg] = Q; rmn[seg] = MN; rmx[seg] = MX; }
  __syncthreads();

  __shared__ float cmn, cinvs, csc;
  if (tid == 0) {
    double St = 0.0, Qt = 0.0;
    float MNt = rmn[0], MXt = rmx[0];
    #pragma unroll
    for (int i = 0; i < 8; ++i) {
      St += rs[i]; Qt += rq[i];
      MNt = fminf(MNt, rmn[i]); MXt = fmaxf(MXt, rmx[i]);
    }
    const double mean = St / 16384.0;
    double var = (Qt - 16384.0 * mean * mean) / 16383.0;
    if (var < 0.0) var = 0.0;
    const float sdev = (float)sqrt(var) + 1e-8f;     // std(ddof=1) + 1e-8
    cmn   = MNt;
    cinvs = 1.0f / sdev;
    csc   = 1.0f / ((MXt - MNt) / sdev + 1e-8f);
  }
  __syncthreads();

  const float mnv = cmn, invs = cinvs, sc = csc;
  for (int i = tid; i < 16384; i += 512) {
    out[i] = ((g[i] - mnv) * invs + 1e-8f) * sc;     // g already transposed
  }
}

extern "C" void kernel_launch(void* const* d_in, const int* in_sizes, int n_in,
                              void* d_out, int out_size, void* d_ws, size_t ws_size,
                              hipStream_t stream) {
  const float* img = (const float*)d_in[0];   // image3d [1,1,128,128,128]
  const float* opa = (const float*)d_in[1];   // opacity [1,1,128,128,128]
  const float* Rm  = (const float*)d_in[2];   // R [1,3,3]
  const float* Tv  = (const float*)d_in[3];   // T [1,3]
  float* out = (float*)d_out;                 // [1,1,128,128] f32 (W,H layout)

  char* wsb = (char*)d_ws;
  float*        g       = (float*)wsb;                    // 64 KB
  double*       bstats  = (double*)(wsb + 65536);         // 8 KB
  unsigned int* counter = (unsigned int*)(wsb + 65536 + 8192);

  hipMemsetAsync(counter, 0, sizeof(unsigned int), stream);
  dvr_kernel<<<256, 512, 0, stream>>>(img, opa, Rm, Tv, g, bstats, counter, out);
}

// Round 4
// 100.049 us; speedup vs baseline: 1.0404x; 1.0404x over previous
//
#include <hip/hip_runtime.h>
#include <math.h>

// DirectVolumeRenderer, single-dispatch, occupancy-restored.
// Block = 64 consecutive x-pixels (half-row) x 16 ray segments x 16 samples
//   = 1024 threads (16 waves). Lane = pixel-x so each gather instruction's 64
//   addresses span ~50-150 consecutive floats (~4-10 cache lines, not 64).
// 256 blocks -> 4096 waves = 16 waves/CU (R3's 8 waves/CU was latency-bound:
//   42us, VALUBusy 15%, FETCH 13MB ~= compulsory).
// Segments composed through LDS (EA recurrence is associative); last block
// (threadfence + atomic counter) reduces 256 stats partials and normalizes.
// g written in transposed (W,H) layout so finalize is coalesced elementwise.

#define FOCAL 1.7320508f

__global__ __launch_bounds__(1024) void dvr_kernel(
    const float* __restrict__ img, const float* __restrict__ opa,
    const float* __restrict__ Rm, const float* __restrict__ Tv,
    float* __restrict__ g, double* __restrict__ bstats,
    unsigned int* __restrict__ counter, float* __restrict__ out)
{
  const int tid  = threadIdx.x;
  const int lane = tid & 63;
  const int seg  = tid >> 6;            // wave id = segment 0..15
  const int b    = blockIdx.x;          // 0..255: half-row id
  const int h    = b >> 1;
  const int w    = ((b & 1) << 6) | lane;

  // camera (row-vector convention): origin = -T @ R^T ; dir_world = dir_cam @ R^T
  const float R00=Rm[0], R01=Rm[1], R02=Rm[2];
  const float R10=Rm[3], R11=Rm[4], R12=Rm[5];
  const float R20=Rm[6], R21=Rm[7], R22=Rm[8];
  const float T0=Tv[0], T1=Tv[1], T2=Tv[2];

  const float ox = -(T0*R00 + T1*R01 + T2*R02);
  const float oy = -(T0*R10 + T1*R11 + T2*R12);
  const float oz = -(T0*R20 + T1*R21 + T2*R22);

  const float gx = 1.0f - (2.0f/127.0f) * (float)w;   // xs = linspace(1,-1,128)
  const float gy = 1.0f - (2.0f/127.0f) * (float)h;
  const float dcx = gx * (1.0f/FOCAL);
  const float dcy = gy * (1.0f/FOCAL);
  const float dwx = dcx*R00 + dcy*R01 + R02;
  const float dwy = dcx*R10 + dcy*R11 + R12;
  const float dwz = dcx*R20 + dcy*R21 + R22;

  // half_extent = (3/128)*127/2 = 1.48828125; voxel coord = (p/he + 1)*63.5
  const float s_he = (1.0f/1.48828125f) * 63.5f;
  const float ax = dwx * s_he, bxc = ox * s_he + 63.5f;
  const float ay = dwy * s_he, byc = oy * s_he + 63.5f;
  const float az = dwz * s_he, bzc = oz * s_he + 63.5f;

  const int p0 = seg << 4;              // 16 samples per segment

  float lp = 1.0f;     // transmittance across this segment
  float accl = 0.0f;   // weighted feature sum relative to segment start

  #pragma unroll 4
  for (int j = 0; j < 16; ++j) {
    const float depth = 2.0f + (4.0f/255.0f) * (float)(p0 + j);  // linspace(2,6,256)
    const float x = bxc + depth * ax;
    const float y = byc + depth * ay;
    const float z = bzc + depth * az;
    const float x0f = floorf(x), y0f = floorf(y), z0f = floorf(z);
    const float wx = x - x0f, wy = y - y0f, wz = z - z0f;
    const int x0 = (int)x0f, y0 = (int)y0f, z0 = (int)z0f;

    float feat = 0.0f, dens = 0.0f;
    if (x0 >= -1 && x0 <= 127 && y0 >= -1 && y0 <= 127 &&
        z0 >= -1 && z0 <= 127) {
      const float fx0 = (x0 >= 0)   ? (1.0f - wx) : 0.0f;
      const float fx1 = (x0 <= 126) ? wx          : 0.0f;
      const float fy0 = (y0 >= 0)   ? (1.0f - wy) : 0.0f;
      const float fy1 = (y0 <= 126) ? wy          : 0.0f;
      const float fz0 = (z0 >= 0)   ? (1.0f - wz) : 0.0f;
      const float fz1 = (z0 <= 126) ? wz          : 0.0f;
      const int ix0 = (x0 >= 0)   ? x0     : 0;
      const int ix1 = (x0 <= 126) ? x0 + 1 : 127;
      const int iy0 = ((y0 >= 0)   ? y0     : 0)   << 7;
      const int iy1 = ((y0 <= 126) ? y0 + 1 : 127) << 7;
      const int iz0 = ((z0 >= 0)   ? z0     : 0)   << 14;
      const int iz1 = ((z0 <= 126) ? z0 + 1 : 127) << 14;

      const int b00 = iz0 + iy0, b01 = iz0 + iy1;
      const int b10 = iz1 + iy0, b11 = iz1 + iy1;
      const float w00 = fz0*fy0, w01 = fz0*fy1, w10 = fz1*fy0, w11 = fz1*fy1;

      feat = w00*(fx0*img[b00+ix0] + fx1*img[b00+ix1])
           + w01*(fx0*img[b01+ix0] + fx1*img[b01+ix1])
           + w10*(fx0*img[b10+ix0] + fx1*img[b10+ix1])
           + w11*(fx0*img[b11+ix0] + fx1*img[b11+ix1]);
      dens = w00*(fx0*opa[b00+ix0] + fx1*opa[b00+ix1])
           + w01*(fx0*opa[b01+ix0] + fx1*opa[b01+ix1])
           + w10*(fx0*opa[b10+ix0] + fx1*opa[b10+ix1])
           + w11*(fx0*opa[b11+ix0] + fx1*opa[b11+ix1]);
    }
    const float d = dens * 0.1f;       // SCALING
    accl += feat * d * lp;             // weight = dens * incoming transmittance
    lp   *= (1.0f - d);                // (1+1e-10)-d == 1-d in f32
  }

  __shared__ float2 slp[16][64];
  slp[seg][lane] = make_float2(accl, lp);
  __syncthreads();

  // ---- per-block combine (wave 0) + stats partial ----
  if (tid < 64) {
    float T = 1.0f, acc = 0.0f;
    #pragma unroll
    for (int s = 0; s < 16; ++s) {
      const float2 v = slp[s][tid];
      acc += v.x * T;
      T *= v.y;
    }
    const int ww = ((b & 1) << 6) | tid;
    g[(ww << 7) + h] = acc;            // transposed (W,H) layout

    double sum = (double)acc;
    double sq  = (double)acc * (double)acc;
    float mn = acc, mx = acc;
    #pragma unroll
    for (int off = 32; off >= 1; off >>= 1) {
      sum += __shfl_xor(sum, off, 64);
      sq  += __shfl_xor(sq,  off, 64);
      mn = fminf(mn, __shfl_xor(mn, off, 64));
      mx = fmaxf(mx, __shfl_xor(mx, off, 64));
    }
    if (tid == 0) {
      bstats[(b << 2) + 0] = sum;
      bstats[(b << 2) + 1] = sq;
      bstats[(b << 2) + 2] = (double)mn;
      bstats[(b << 2) + 3] = (double)mx;
    }
  }
  __syncthreads();

  // ---- last-block-finalize handshake ----
  __shared__ int is_last;
  if (tid == 0) {
    __threadfence();                                  // publish g + bstats
    const unsigned int old = atomicAdd(counter, 1u);  // device-scope
    is_last = (old == gridDim.x - 1) ? 1 : 0;
  }
  __syncthreads();
  if (!is_last) return;
  __threadfence();                                    // acquire

  // ---- global stats reduction (256 partials) ----
  double S = 0.0, Q = 0.0;
  float MN = 3.402823466e38f, MX = -3.402823466e38f;
  if (tid < 256) {
    S  = bstats[(tid << 2) + 0];
    Q  = bstats[(tid << 2) + 1];
    MN = (float)bstats[(tid << 2) + 2];
    MX = (float)bstats[(tid << 2) + 3];
  }
  #pragma unroll
  for (int off = 32; off >= 1; off >>= 1) {
    S += __shfl_xor(S, off, 64);
    Q += __shfl_xor(Q, off, 64);
    MN = fminf(MN, __shfl_xor(MN, off, 64));
    MX = fmaxf(MX, __shfl_xor(MX, off, 64));
  }
  __shared__ double rs[16], rq[16];
  __shared__ float rmn[16], rmx[16];
  if (lane == 0) { rs[seg] = S; rq[seg] = Q; rmn[seg] = MN; rmx[seg] = MX; }
  __syncthreads();

  __shared__ float cmn, cinvs, csc;
  if (tid == 0) {
    double St = 0.0, Qt = 0.0;
    float MNt = rmn[0], MXt = rmx[0];
    #pragma unroll
    for (int i = 0; i < 4; ++i) {       // only waves 0..3 held partials
      St += rs[i]; Qt += rq[i];
      MNt = fminf(MNt, rmn[i]); MXt = fmaxf(MXt, rmx[i]);
    }
    const double mean = St / 16384.0;
    double var = (Qt - 16384.0 * mean * mean) / 16383.0;
    if (var < 0.0) var = 0.0;
    const float sdev = (float)sqrt(var) + 1e-8f;     // std(ddof=1) + 1e-8
    cmn   = MNt;
    cinvs = 1.0f / sdev;
    csc   = 1.0f / ((MXt - MNt) / sdev + 1e-8f);
  }
  __syncthreads();

  const float mnv = cmn, invs = cinvs, sc = csc;
  for (int i = tid; i < 16384; i += 1024) {
    out[i] = ((g[i] - mnv) * invs + 1e-8f) * sc;     // g already transposed
  }
}

extern "C" void kernel_launch(void* const* d_in, const int* in_sizes, int n_in,
                              void* d_out, int out_size, void* d_ws, size_t ws_size,
                              hipStream_t stream) {
  const float* img = (const float*)d_in[0];   // image3d [1,1,128,128,128]
  const float* opa = (const float*)d_in[1];   // opacity [1,1,128,128,128]
  const float* Rm  = (const float*)d_in[2];   // R [1,3,3]
  const float* Tv  = (const float*)d_in[3];   // T [1,3]
  float* out = (float*)d_out;                 // [1,1,128,128] f32 (W,H layout)

  char* wsb = (char*)d_ws;
  float*        g       = (float*)wsb;                    // 64 KB
  double*       bstats  = (double*)(wsb + 65536);         // 8 KB
  unsigned int* counter = (unsigned int*)(wsb + 65536 + 8192);

  hipMemsetAsync(counter, 0, sizeof(unsigned int), stream);
  dvr_kernel<<<256, 1024, 0, stream>>>(img, opa, Rm, Tv, g, bstats, counter, out);
}